// Round 15
// baseline (323.533 us; speedup 1.0000x reference)
//
#include <hip/hip_runtime.h>
#include <hip/hip_bf16.h>
#include <math.h>

typedef __hip_bfloat16 bf16;
typedef unsigned short u16;

__device__ __forceinline__ float b2f(bf16 v){ return __bfloat162float(v); }
__device__ __forceinline__ u16 f2bu(float f){
  bf16 h = __float2bfloat16(f);
  return *reinterpret_cast<u16*>(&h);
}
__device__ __forceinline__ float bu2f(u16 u){
  bf16 h = *reinterpret_cast<bf16*>(&u);
  return __bfloat162float(h);
}
__device__ __forceinline__ float eluf(float x){ return x > 0.f ? x : __expf(x) - 1.f; }
__device__ __forceinline__ float lrelu(float x){ return x > 0.f ? x : 0.2f * x; }
__device__ __forceinline__ float ldr(const void* p, int i, int f){
  return f ? ((const float*)p)[i] : b2f(((const bf16*)p)[i]);
}
__device__ __forceinline__ float rl_f(float v, int lane){
  return __int_as_float(__builtin_amdgcn_readlane(__float_as_int(v), lane));
}

// ---------------- detect dtype + zero counts/fp (merged) --------------------
__global__ void detect_zero_k(const u16* __restrict__ x, int nprobe, int* __restrict__ flag,
                              int* __restrict__ counts, float* __restrict__ fp, int n){
  int i = blockIdx.x * 256 + threadIdx.x;
  if (i < n) counts[i] = 0;
  if (i < 512) fp[i] = 0.f;
  if (blockIdx.x == 0){
    __shared__ int bad_s;
    if (threadIdx.x == 0) bad_s = 0;
    __syncthreads();
    int bad = 0;
    for (int k = threadIdx.x; k < nprobe; k += 256){
      int ex = (x[k] >> 7) & 0xFF;
      if (ex >= 0xC6) bad = 1;
    }
    if (bad) atomicOr(&bad_s, 1);
    __syncthreads();
    if (threadIdx.x == 0) *flag = bad_s;
  }
}

// ---------------- convert + count_edges + prep4 (merged) --------------------
struct ConvDesc {
  const void* src[21];
  int off[22];
};

__global__ void convcnt_k(ConvDesc d, float* __restrict__ out, const int* __restrict__ flag,
                          int total, const int* __restrict__ ei, int E, int n,
                          int* __restrict__ counts,
                          const void* __restrict__ W4r, const void* __restrict__ as4r,
                          const void* __restrict__ ad4r, float* __restrict__ avs,
                          float* __restrict__ avd, float* __restrict__ Wz,
                          int CB, int EB){
  int b = blockIdx.x;
  int f = *flag;
  if (b < CB){
    int i = b * 256 + threadIdx.x;
    if (i >= total) return;
    int a = 0;
    while (i >= d.off[a + 1]) ++a;
    out[i] = ldr(d.src[a], i - d.off[a], f);
  } else if (b < CB + EB){
    int e = (b - CB) * 256 + threadIdx.x;
    if (e >= E + n) return;
    int dd = (e < E) ? ei[E + e] : (e - E);
    atomicAdd(&counts[dd], 1);
  } else {
    int pb = b - CB - EB;                     // 0..63
    int g = pb * 256 + threadIdx.x;           // < 16384
    int r = g >> 6, c = g & 63;
    int h = r >> 6, k = r & 63;
    Wz[r * 64 + c] = 0.25f * ldr(W4r, k * 256 + h * 64 + c, f);
    if (pb == 0){
      int t = threadIdx.x;
      int th = t >> 6, tk = t & 63;
      float s1 = 0.f, s2 = 0.f;
      for (int cc = 0; cc < 64; ++cc){
        float w = ldr(W4r, tk * 256 + th * 64 + cc, f);
        s1 += w * ldr(as4r, th * 64 + cc, f);
        s2 += w * ldr(ad4r, th * 64 + cc, f);
      }
      avs[t] = s1;
      avd[t] = s2;
    }
  }
}

// ---------------- CSR scan + scatter ----------------

__global__ void scan_k(const int* __restrict__ counts_in, int* __restrict__ counts_zero,
                       int* __restrict__ row_ptr, int n){
  __shared__ int psum[1024];
  int t = threadIdx.x;
  int chunk = (n + 1023) >> 10;
  int beg = t * chunk;
  int end = beg + chunk; if (end > n) end = n;
  int s = 0;
  for (int i = beg; i < end; ++i) s += counts_in[i];
  psum[t] = s;
  __syncthreads();
  for (int off = 1; off < 1024; off <<= 1){
    int v = (t >= off) ? psum[t - off] : 0;
    __syncthreads();
    psum[t] += v;
    __syncthreads();
  }
  int run = psum[t] - s;
  for (int i = beg; i < end; ++i){
    row_ptr[i] = run; run += counts_in[i]; counts_zero[i] = 0;
  }
  if (beg < n && end == n) row_ptr[n] = run;
}

__global__ void scatter_k(const int* __restrict__ ei, const int* __restrict__ row_ptr,
                          int* __restrict__ fill, int* __restrict__ esrc, int E, int n){
  int e = blockIdx.x * blockDim.x + threadIdx.x;
  if (e >= E + n) return;
  int s, d;
  if (e < E){ s = ei[e]; d = ei[E + e]; } else { s = e - E; d = s; }
  int pos = row_ptr[d] + atomicAdd(&fill[d], 1);
  esrc[pos] = s;
}

// ---------------- small-tile linear: 16 nodes/block ----------
template<int K, bool ELU, bool ALPHA, bool OB16, bool IB16>
__global__ void linear_s_k(const float* __restrict__ Xf, const u16* __restrict__ Xb,
                           const float* __restrict__ W, const float* __restrict__ bias,
                           const float* __restrict__ a_src, const float* __restrict__ a_dst,
                           float* __restrict__ Y, u16* __restrict__ Yb,
                           float* __restrict__ asrc, float* __restrict__ adst, int n){
  constexpr int KC = (K > 64) ? 64 : K;
  __shared__ float wl[KC * 64];
  __shared__ float xr[16][KC + 4];
  int base = blockIdx.x * 16;
  int t = threadIdx.x;
  int lane = t & 63, wv = t >> 6;
  int node = wv * 4 + (lane >> 4);
  int jj = lane & 15;
  float ax = 0.f, ay = 0.f, az = 0.f, aw = 0.f;
  for (int kb = 0; kb < K; kb += KC){
    if (kb) __syncthreads();
    for (int q = t; q < KC * 16; q += 256)
      ((float4*)wl)[q] = ((const float4*)(W + (kb + (q >> 4)) * 64))[q & 15];
    for (int q = t; q < 16 * (KC / 4); q += 256){
      int nd = q / (KC / 4);
      int k4 = q - nd * (KC / 4);
      if (IB16){
        float4 v = make_float4(0.f, 0.f, 0.f, 0.f);
        if (base + nd < n){
          ushort4 v4 = *(const ushort4*)(Xb + (base + nd) * K + kb + k4 * 4);
          v = make_float4(bu2f(v4.x), bu2f(v4.y), bu2f(v4.z), bu2f(v4.w));
        }
        *(float4*)(&xr[nd][k4 * 4]) = v;
      } else {
        float4 v = make_float4(0.f, 0.f, 0.f, 0.f);
        if (base + nd < n) v = *(const float4*)(Xf + (base + nd) * K + kb + k4 * 4);
        *(float4*)(&xr[nd][k4 * 4]) = v;
      }
    }
    __syncthreads();
#pragma unroll 4
    for (int k4 = 0; k4 < KC / 4; ++k4){
      float4 xv = *(const float4*)(&xr[node][k4 * 4]);
      float4 w0 = ((const float4*)wl)[(k4 * 4 + 0) * 16 + jj];
      float4 w1 = ((const float4*)wl)[(k4 * 4 + 1) * 16 + jj];
      float4 w2 = ((const float4*)wl)[(k4 * 4 + 2) * 16 + jj];
      float4 w3 = ((const float4*)wl)[(k4 * 4 + 3) * 16 + jj];
      ax += xv.x * w0.x + xv.y * w1.x + xv.z * w2.x + xv.w * w3.x;
      ay += xv.x * w0.y + xv.y * w1.y + xv.z * w2.y + xv.w * w3.y;
      az += xv.x * w0.z + xv.y * w1.z + xv.z * w2.z + xv.w * w3.z;
      aw += xv.x * w0.w + xv.y * w1.w + xv.z * w2.w + xv.w * w3.w;
    }
  }
  int gn = base + node;
  if (gn < n){
    float vx = ax, vy = ay, vz = az, vw = aw;
    if (ELU){
      float4 b = ((const float4*)bias)[jj];
      vx = eluf(ax + b.x); vy = eluf(ay + b.y); vz = eluf(az + b.z); vw = eluf(aw + b.w);
    }
    if (OB16){
      ushort4 o4;
      o4.x = f2bu(vx); o4.y = f2bu(vy); o4.z = f2bu(vz); o4.w = f2bu(vw);
      ((ushort4*)(Yb + gn * 64))[jj] = o4;
    } else {
      ((float4*)(Y + gn * 64))[jj] = make_float4(vx, vy, vz, vw);
    }
  }
  if (ALPHA){
    float4 as = *(const float4*)(a_src + 4 * jj);
    float4 ad = *(const float4*)(a_dst + 4 * jj);
    float s1 = ax * as.x + ay * as.y + az * as.z + aw * as.w;
    float s2 = ax * ad.x + ay * ad.y + az * ad.z + aw * ad.w;
    s1 += __shfl_xor(s1, 1);
    s2 += __shfl_xor(s2, 1);
    if (gn < n){
      int h = jj >> 1;
      if ((jj & 1) == 0) asrc[gn * 8 + h] = s1;
      else               adst[gn * 8 + h] = s2;
    }
  }
}

// ---------------- fused agg8, QUAD-PACKED gather ----------------------------
// Round-15: old gather loaded each edge row as 64-lane x 2B (128B/instr,
// worst width). Now lane owns channel quad cp (8B); wave quarters process 4
// edges per ushort4 load (512B/instr) => 2 loads per 8-edge batch (was 8).
// Weight/row broadcasts: 2+2 bpermute (was 8 swizzle). Online-softmax scale
// and sw hop weight-layout -> channel-layout via 1 shfl each. Partial batches
// need no branch: OOB weights are 0, row 0 safely loadable.
template<int NEXT>
__global__ void agg8f_k(const u16* __restrict__ hlin, const float* __restrict__ asrc,
                        const float* __restrict__ adst, const int* __restrict__ row_ptr,
                        const int* __restrict__ esrc, const float* __restrict__ bias,
                        const float* __restrict__ Wn,
                        const float* __restrict__ a_srcn, const float* __restrict__ a_dstn,
                        const float* __restrict__ avs, const float* __restrict__ avd,
                        u16* __restrict__ hout, u16* __restrict__ ylin,
                        float* __restrict__ asrco, float* __restrict__ adsto, int n){
  __shared__ float wl[NEXT == 1 ? 4096 : 1];
  __shared__ float os[4][64];
  if (NEXT == 1){
    for (int q = threadIdx.x; q < 1024; q += 256)
      ((float4*)wl)[q] = ((const float4*)Wn)[q];
    __syncthreads();
  }
  int node = (blockIdx.x * blockDim.x + threadIdx.x) >> 6;
  if (node >= n) return;
  int lane = threadIdx.x & 63;
  int wv = (threadIdx.x >> 6) & 3;
  int h = lane >> 3;                 // weight layout: head
  int j = lane & 7;                  //               edge slot
  int cp = lane & 15;                // gather layout: channel quad
  int q  = lane >> 4;                //               wave quarter
  int hh = cp >> 1;                  // head of channels 4cp..4cp+3
  int wlane0 = hh * 8 + q;           // w(edge q, head hh)
  int wlane1 = hh * 8 + 4 + q;       // w(edge 4+q, head hh)
  int sclane = hh * 8;               // per-head scale/sw holder
  int beg = row_ptr[node], end = row_ptr[node + 1];
  float ad = adst[node * 8 + h];

  float m = -INFINITY, swp = 0.f;
  float4 acc = make_float4(0.f, 0.f, 0.f, 0.f);
  int p0 = beg + j;
  int   s_nx = 0;
  float l_nx = -INFINITY;
  if (p0 < end){ s_nx = esrc[p0]; l_nx = lrelu(asrc[s_nx * 8 + h] + ad); }
  for (int b0 = beg; b0 < end; b0 += 8){
    int   s = s_nx;
    float l = l_nx;
    int p2 = b0 + 8 + j;
    s_nx = 0; l_nx = -INFINITY;
    if (p2 < end){ s_nx = esrc[p2]; l_nx = lrelu(asrc[s_nx * 8 + h] + ad); }
    float bm = l;
    bm = fmaxf(bm, __shfl_xor(bm, 1));
    bm = fmaxf(bm, __shfl_xor(bm, 2));
    bm = fmaxf(bm, __shfl_xor(bm, 4));
    float mn = fmaxf(m, bm);
    float scale = __expf(m - mn);
    swp *= scale; m = mn;
    float w = (b0 + j < end) ? __expf(l - m) : 0.f;
    swp += w;
    // gather (channel-quad layout)
    float scale_g = __shfl(scale, sclane);
    acc.x *= scale_g; acc.y *= scale_g; acc.z *= scale_g; acc.w *= scale_g;
    int s0 = __shfl(s, q);
    int s1 = __shfl(s, 4 + q);
    float w0 = __shfl(w, wlane0);
    float w1 = __shfl(w, wlane1);
    ushort4 hv0 = *(const ushort4*)(hlin + s0 * 64 + cp * 4);
    ushort4 hv1 = *(const ushort4*)(hlin + s1 * 64 + cp * 4);
    acc.x += bu2f(hv0.x) * w0 + bu2f(hv1.x) * w1;
    acc.y += bu2f(hv0.y) * w0 + bu2f(hv1.y) * w1;
    acc.z += bu2f(hv0.z) * w0 + bu2f(hv1.z) * w1;
    acc.w += bu2f(hv0.w) * w0 + bu2f(hv1.w) * w1;
  }
  // combine quarters (all lanes end with full sums)
  acc.x += __shfl_xor(acc.x, 16); acc.x += __shfl_xor(acc.x, 32);
  acc.y += __shfl_xor(acc.y, 16); acc.y += __shfl_xor(acc.y, 32);
  acc.z += __shfl_xor(acc.z, 16); acc.z += __shfl_xor(acc.z, 32);
  acc.w += __shfl_xor(acc.w, 16); acc.w += __shfl_xor(acc.w, 32);
  swp += __shfl_xor(swp, 1);
  swp += __shfl_xor(swp, 2);
  swp += __shfl_xor(swp, 4);
  float sw_g = __shfl(swp, sclane);
  float4 bv = ((const float4*)bias)[cp];
  float4 o4;
  o4.x = eluf(acc.x / sw_g + bv.x);
  o4.y = eluf(acc.y / sw_g + bv.y);
  o4.z = eluf(acc.z / sw_g + bv.z);
  o4.w = eluf(acc.w / sw_g + bv.w);

  if (NEXT == 1){
    if (lane < 16) *(float4*)(&os[wv][cp * 4]) = o4;   // same-wave RAW
    int jj = lane & 15, kk = lane >> 4;
    float ax = 0.f, ay = 0.f, az = 0.f, aw = 0.f;
#pragma unroll
    for (int k = 0; k < 16; ++k){
      float xv = os[wv][kk * 16 + k];
      float4 w = ((const float4*)wl)[(kk * 16 + k) * 16 + jj];
      ax += xv * w.x; ay += xv * w.y; az += xv * w.z; aw += xv * w.w;
    }
    ax += __shfl_xor(ax, 16); ax += __shfl_xor(ax, 32);
    ay += __shfl_xor(ay, 16); ay += __shfl_xor(ay, 32);
    az += __shfl_xor(az, 16); az += __shfl_xor(az, 32);
    aw += __shfl_xor(aw, 16); aw += __shfl_xor(aw, 32);
    if (lane < 16){
      ushort4 y4;
      y4.x = f2bu(ax); y4.y = f2bu(ay); y4.z = f2bu(az); y4.w = f2bu(aw);
      ((ushort4*)(ylin + node * 64))[jj] = y4;
      float4 as = *(const float4*)(a_srcn + 4 * jj);
      float4 adn = *(const float4*)(a_dstn + 4 * jj);
      float s1 = ax * as.x + ay * as.y + az * as.z + aw * as.w;
      float s2 = ax * adn.x + ay * adn.y + az * adn.z + aw * adn.w;
      s1 += __shfl_xor(s1, 1);
      s2 += __shfl_xor(s2, 1);
      int nh = jj >> 1;
      if ((jj & 1) == 0) asrco[node * 8 + nh] = s1;
      else               adsto[node * 8 + nh] = s2;
    }
  } else {
    if (lane < 16){
      ushort4 ho;
      ho.x = f2bu(o4.x); ho.y = f2bu(o4.y); ho.z = f2bu(o4.z); ho.w = f2bu(o4.w);
      ((ushort4*)(hout + node * 64))[cp] = ho;
      *(float4*)(&os[wv][cp * 4]) = o4;
    }
    int t8 = lane & 7, ah = (lane >> 3) & 3, sd = lane >> 5;
    const float* av = sd ? avd : avs;
    float part = 0.f;
#pragma unroll
    for (int c = 0; c < 8; ++c)
      part += os[wv][t8 * 8 + c] * av[ah * 64 + t8 * 8 + c];
    part += __shfl_xor(part, 1);
    part += __shfl_xor(part, 2);
    part += __shfl_xor(part, 4);
    if (t8 == 0){
      if (sd == 0) asrco[node * 4 + ah] = part;
      else         adsto[node * 4 + ah] = part;
    }
  }
}

// Layer-4 gather: readlane form (DS-free broadcasts), bf16 h3 rows, z bf16.
__global__ void aggz_k(const u16* __restrict__ h3, const float* __restrict__ asrc,
                       const float* __restrict__ adst, const int* __restrict__ row_ptr,
                       const int* __restrict__ esrc, u16* __restrict__ z, int n){
  int node = (blockIdx.x * blockDim.x + threadIdx.x) >> 6;
  if (node >= n) return;
  int lane = threadIdx.x & 63;
  int h = lane >> 4, j = lane & 15;
  int beg = row_ptr[node], end = row_ptr[node + 1];
  float4 adv = *(const float4*)(adst + node * 4);
  float adh = h == 0 ? adv.x : h == 1 ? adv.y : h == 2 ? adv.z : adv.w;

  float m = -INFINITY;
  float acc0 = 0.f, acc1 = 0.f, acc2 = 0.f, acc3 = 0.f, swp = 0.f;
  int p0 = beg + j;
  int   s_nx = 0;
  float l_nx = -INFINITY;
  if (p0 < end){ s_nx = esrc[p0]; l_nx = lrelu(asrc[s_nx * 4 + h] + adh); }
  for (int b0 = beg; b0 < end; b0 += 16){
    int   s = s_nx;
    float l = l_nx;
    int p2 = b0 + 16 + j;
    s_nx = 0; l_nx = -INFINITY;
    if (p2 < end){ s_nx = esrc[p2]; l_nx = lrelu(asrc[s_nx * 4 + h] + adh); }
    float bm = l;
    bm = fmaxf(bm, __shfl_xor(bm, 1));
    bm = fmaxf(bm, __shfl_xor(bm, 2));
    bm = fmaxf(bm, __shfl_xor(bm, 4));
    bm = fmaxf(bm, __shfl_xor(bm, 8));
    float mn = fmaxf(m, bm);
    float scale = __expf(m - mn);
    acc0 *= scale; acc1 *= scale; acc2 *= scale; acc3 *= scale;
    swp *= scale; m = mn;
    float w = (b0 + j < end) ? __expf(l - m) : 0.f;
    swp += w;
    int cnt = end - b0; if (cnt > 16) cnt = 16;
#pragma unroll 4
    for (int i = 0; i < cnt; ++i){
      int   si = __builtin_amdgcn_readlane(s, i);
      float hv = bu2f(h3[si * 64 + lane]);
      float w0 = rl_f(w, i);
      float w1 = rl_f(w, 16 + i);
      float w2 = rl_f(w, 32 + i);
      float w3 = rl_f(w, 48 + i);
      acc0 += hv * w0; acc1 += hv * w1; acc2 += hv * w2; acc3 += hv * w3;
    }
  }
  swp += __shfl_xor(swp, 1);
  swp += __shfl_xor(swp, 2);
  swp += __shfl_xor(swp, 4);
  swp += __shfl_xor(swp, 8);
  float sw0 = __shfl(swp, 0), sw1 = __shfl(swp, 16);
  float sw2 = __shfl(swp, 32), sw3 = __shfl(swp, 48);
  int zb = node * 256;
  z[zb + lane]        = f2bu(acc0 / sw0);
  z[zb + 64 + lane]   = f2bu(acc1 / sw1);
  z[zb + 128 + lane]  = f2bu(acc2 / sw2);
  z[zb + 192 + lane]  = f2bu(acc3 / sw3);
}

// ---------------- pooling + head ----------------

__global__ void pool_k(const float* __restrict__ h, const int* __restrict__ fidx,
                       const int* __restrict__ flag_arr, float* __restrict__ fp, int m){
  __shared__ float acc[512];
  for (int t = threadIdx.x; t < 512; t += blockDim.x) acc[t] = 0.f;
  __syncthreads();
  int lane = threadIdx.x & 63;
  int wave = (blockIdx.x * blockDim.x + threadIdx.x) >> 6;
  int nwaves = (gridDim.x * blockDim.x) >> 6;
  for (int i = wave; i < m; i += nwaves){
    int g = flag_arr[i];
    int node = fidx[i];
    atomicAdd(&acc[g * 64 + lane], h[node * 64 + lane]);
  }
  __syncthreads();
  for (int t = threadIdx.x; t < 512; t += blockDim.x)
    atomicAdd(&fp[t], acc[t]);
}

__global__ void final_k(const float* __restrict__ fp, const float* __restrict__ h,
                        const int* __restrict__ dec,
                        const float* __restrict__ Wp, const float* __restrict__ Wt,
                        const float* __restrict__ Wo, const float* __restrict__ bo,
                        void* __restrict__ out, const int* __restrict__ dflag){
  int g = threadIdx.x >> 6;
  int j = threadIdx.x & 63;
  const float* fr = fp + g * 64;
  const float* tr = h + dec[g] * 64;
  float a = 0.f, b = 0.f;
  for (int k = 0; k < 64; ++k){
    a += fr[k] * Wp[k * 64 + j];
    b += tr[k] * Wt[k * 64 + j];
  }
  float v = eluf(a) * Wo[j] + eluf(b) * Wo[64 + j];
  for (int off = 32; off > 0; off >>= 1) v += __shfl_down(v, off);
  if (j == 0){
    float r = v + bo[0];
    if (*dflag) ((float*)out)[g] = r;
    else        ((bf16*)out)[g] = __float2bfloat16(r);
  }
}

// ---------------- launch (12 dispatches) ----------------

extern "C" void kernel_launch(void* const* d_in, const int* in_sizes, int n_in,
                              void* d_out, int out_size, void* d_ws, size_t ws_size,
                              hipStream_t stream) {
  const int*  ei    = (const int*)d_in[1];
  const int*  fidx  = (const int*)d_in[2];
  const int*  flagg = (const int*)d_in[3];
  const int*  dec   = (const int*)d_in[4];

  const int N = in_sizes[0] / 16;   // 20000
  const int E = in_sizes[1] / 2;    // 320000
  const int M = in_sizes[2];        // 8000
  const int ET = E + N;

  const int fidxs[21] = {0,5,6,7,8,9,10,11,12,13,14,15,16,17,18,19,20,21,22,23,24};
  ConvDesc cd;
  int tot = 0;
  for (int k = 0; k < 21; ++k){
    cd.src[k] = d_in[fidxs[k]];
    cd.off[k] = tot;
    tot += in_sizes[fidxs[k]];
  }
  cd.off[21] = tot;

  char* p = (char*)d_ws;
  auto carve = [&](size_t bytes) -> void* {
    void* r = (void*)p;
    p += (bytes + 255) & ~(size_t)255;
    return r;
  };
  int*   dflag   = (int*)carve(4);
  float* conv    = (float*)carve((size_t)tot * 4);
  u16*   hlA     = (u16*)carve((size_t)N * 64 * 2);
  u16*   hlB     = (u16*)carve((size_t)N * 64 * 2);
  u16*   h3buf   = (u16*)carve((size_t)N * 64 * 2);
  u16*   zbuf    = (u16*)carve((size_t)N * 256 * 2);
  float* h4buf   = (float*)carve((size_t)N * 64 * 4);
  float* asrcA   = (float*)carve((size_t)N * 8 * 4);
  float* adstA   = (float*)carve((size_t)N * 8 * 4);
  float* asrcB   = (float*)carve((size_t)N * 8 * 4);
  float* adstB   = (float*)carve((size_t)N * 8 * 4);
  int*   counts  = (int*)carve((size_t)N * 4);
  int*   row_ptr = (int*)carve((size_t)(N + 1) * 4);
  int*   esrc    = (int*)carve((size_t)ET * 4);
  float* fp      = (float*)carve(8 * 64 * 4);
  float* avs     = (float*)carve(256 * 4);
  float* avd     = (float*)carve(256 * 4);
  float* wz      = (float*)carve(256 * 64 * 4);

  if ((size_t)(p - (char*)d_ws) > ws_size) return;

  const float* cW1 = conv + cd.off[1],  *cas1 = conv + cd.off[2],  *cad1 = conv + cd.off[3],  *cb1 = conv + cd.off[4];
  const float* cW2 = conv + cd.off[5],  *cas2 = conv + cd.off[6],  *cad2 = conv + cd.off[7],  *cb2 = conv + cd.off[8];
  const float* cW3 = conv + cd.off[9],  *cas3 = conv + cd.off[10], *cad3 = conv + cd.off[11], *cb3 = conv + cd.off[12];
  const float* cb4 = conv + cd.off[16];
  const float* cWp = conv + cd.off[17], *cWt = conv + cd.off[18], *cWo = conv + cd.off[19], *cbo = conv + cd.off[20];
  const float* xf  = conv + cd.off[0];

  const int TB = 256;
  int nprobe = in_sizes[0] < 4096 ? in_sizes[0] : 4096;
  int zb_blocks = (N + 255) / 256;
  int CB = (tot + 255) / 256;
  int EB = (ET + 255) / 256;

  detect_zero_k<<<zb_blocks, TB, 0, stream>>>((const u16*)d_in[0], nprobe, dflag, counts, fp, N);
  convcnt_k<<<CB + EB + 64, TB, 0, stream>>>(cd, conv, dflag, tot, ei, E, N, counts,
                                             d_in[17], d_in[18], d_in[19], avs, avd, wz, CB, EB);
  scan_k<<<1, 1024, 0, stream>>>(counts, counts, row_ptr, N);
  scatter_k<<<EB, TB, 0, stream>>>(ei, row_ptr, counts, esrc, E, N);

  int agg_blocks = (N * 64 + TB - 1) / TB;
  int ls_blocks  = (N + 15) / 16;

  linear_s_k<16, false, true, true, false><<<ls_blocks, TB, 0, stream>>>(
      xf, nullptr, cW1, nullptr, cas1, cad1, nullptr, hlA, asrcA, adstA, N);
  agg8f_k<1><<<agg_blocks, TB, 0, stream>>>(hlA, asrcA, adstA, row_ptr, esrc, cb1,
                                            cW2, cas2, cad2, nullptr, nullptr,
                                            nullptr, hlB, asrcB, adstB, N);
  agg8f_k<1><<<agg_blocks, TB, 0, stream>>>(hlB, asrcB, adstB, row_ptr, esrc, cb2,
                                            cW3, cas3, cad3, nullptr, nullptr,
                                            nullptr, hlA, asrcA, adstA, N);
  agg8f_k<2><<<agg_blocks, TB, 0, stream>>>(hlA, asrcA, adstA, row_ptr, esrc, cb3,
                                            nullptr, nullptr, nullptr, avs, avd,
                                            h3buf, nullptr, asrcB, adstB, N);
  aggz_k<<<agg_blocks, TB, 0, stream>>>(h3buf, asrcB, adstB, row_ptr, esrc, zbuf, N);
  linear_s_k<256, true, false, false, true><<<ls_blocks, TB, 0, stream>>>(
      nullptr, zbuf, wz, cb4, nullptr, nullptr, h4buf, nullptr, nullptr, nullptr, N);
  pool_k<<<64, TB, 0, stream>>>(h4buf, fidx, flagg, fp, M);
  final_k<<<1, 512, 0, stream>>>(fp, h4buf, dec, cWp, cWt, cWo, cbo, d_out, dflag);
}

// Round 16
// 321.775 us; speedup vs baseline: 1.0055x; 1.0055x over previous
//
#include <hip/hip_runtime.h>
#include <hip/hip_bf16.h>
#include <math.h>

typedef __hip_bfloat16 bf16;
typedef unsigned short u16;

__device__ __forceinline__ float b2f(bf16 v){ return __bfloat162float(v); }
__device__ __forceinline__ u16 f2bu(float f){
  bf16 h = __float2bfloat16(f);
  return *reinterpret_cast<u16*>(&h);
}
__device__ __forceinline__ float bu2f(u16 u){
  bf16 h = *reinterpret_cast<bf16*>(&u);
  return __bfloat162float(h);
}
__device__ __forceinline__ float eluf(float x){ return x > 0.f ? x : __expf(x) - 1.f; }
__device__ __forceinline__ float lrelu(float x){ return x > 0.f ? x : 0.2f * x; }
__device__ __forceinline__ float ldr(const void* p, int i, int f){
  return f ? ((const float*)p)[i] : b2f(((const bf16*)p)[i]);
}
__device__ __forceinline__ float rl_f(float v, int lane){
  return __int_as_float(__builtin_amdgcn_readlane(__float_as_int(v), lane));
}

// ---- DPP cross-lane (VALU pipe, not DS) -----------------------------------
// quad_perm xor1=0xB1, xor2=0x4E; row_half_mirror(^7)=0x141; row_mirror(^15)=0x140
#define DPP_F(x, ctrl) __int_as_float(__builtin_amdgcn_update_dpp(0, __float_as_int(x), (ctrl), 0xF, 0xF, true))
__device__ __forceinline__ float dpp_max8(float x){
  x = fmaxf(x, DPP_F(x, 0xB1));
  x = fmaxf(x, DPP_F(x, 0x4E));
  x = fmaxf(x, DPP_F(x, 0x141));
  return x;
}
__device__ __forceinline__ float dpp_sum8(float x){
  x += DPP_F(x, 0xB1);
  x += DPP_F(x, 0x4E);
  x += DPP_F(x, 0x141);
  return x;
}
__device__ __forceinline__ float dpp_max16(float x){
  x = fmaxf(x, DPP_F(x, 0xB1));
  x = fmaxf(x, DPP_F(x, 0x4E));
  x = fmaxf(x, DPP_F(x, 0x141));
  x = fmaxf(x, DPP_F(x, 0x140));
  return x;
}
__device__ __forceinline__ float dpp_sum16(float x){
  x += DPP_F(x, 0xB1);
  x += DPP_F(x, 0x4E);
  x += DPP_F(x, 0x141);
  x += DPP_F(x, 0x140);
  return x;
}
__device__ __forceinline__ float dpp_addx1(float x){ return x + DPP_F(x, 0xB1); }

// ---------------- detect dtype + zero counts/fp (merged) --------------------
__global__ void detect_zero_k(const u16* __restrict__ x, int nprobe, int* __restrict__ flag,
                              int* __restrict__ counts, float* __restrict__ fp, int n){
  int i = blockIdx.x * 256 + threadIdx.x;
  if (i < n) counts[i] = 0;
  if (i < 512) fp[i] = 0.f;
  if (blockIdx.x == 0){
    __shared__ int bad_s;
    if (threadIdx.x == 0) bad_s = 0;
    __syncthreads();
    int bad = 0;
    for (int k = threadIdx.x; k < nprobe; k += 256){
      int ex = (x[k] >> 7) & 0xFF;
      if (ex >= 0xC6) bad = 1;
    }
    if (bad) atomicOr(&bad_s, 1);
    __syncthreads();
    if (threadIdx.x == 0) *flag = bad_s;
  }
}

// ---------------- convert(weights only) + count_edges + prep4 ---------------
struct ConvDesc {
  const void* src[17];
  int off[18];
};

__global__ void convcnt_k(ConvDesc d, float* __restrict__ out, const int* __restrict__ flag,
                          int total, const int* __restrict__ ei, int E, int n,
                          int* __restrict__ counts,
                          const void* __restrict__ W4r, const void* __restrict__ as4r,
                          const void* __restrict__ ad4r, float* __restrict__ avs,
                          float* __restrict__ avd, float* __restrict__ Wz,
                          int CB, int EB){
  int b = blockIdx.x;
  int f = *flag;
  if (b < CB){
    int i = b * 256 + threadIdx.x;
    if (i >= total) return;
    int a = 0;
    while (i >= d.off[a + 1]) ++a;
    out[i] = ldr(d.src[a], i - d.off[a], f);
  } else if (b < CB + EB){
    int e = (b - CB) * 256 + threadIdx.x;
    if (e >= E + n) return;
    int dd = (e < E) ? ei[E + e] : (e - E);
    atomicAdd(&counts[dd], 1);
  } else {
    int pb = b - CB - EB;                     // 0..63
    int g = pb * 256 + threadIdx.x;           // < 16384
    int r = g >> 6, c = g & 63;
    int h = r >> 6, k = r & 63;
    Wz[r * 64 + c] = 0.25f * ldr(W4r, k * 256 + h * 64 + c, f);
    if (pb == 0){
      int t = threadIdx.x;
      int th = t >> 6, tk = t & 63;
      float s1 = 0.f, s2 = 0.f;
      for (int cc = 0; cc < 64; ++cc){
        float w = ldr(W4r, tk * 256 + th * 64 + cc, f);
        s1 += w * ldr(as4r, th * 64 + cc, f);
        s2 += w * ldr(ad4r, th * 64 + cc, f);
      }
      avs[t] = s1;
      avd[t] = s2;
    }
  }
}

// ---------------- CSR scan + scatter ----------------

__global__ void scan_k(const int* __restrict__ counts_in, int* __restrict__ counts_zero,
                       int* __restrict__ row_ptr, int n){
  __shared__ int psum[1024];
  int t = threadIdx.x;
  int chunk = (n + 1023) >> 10;
  int beg = t * chunk;
  int end = beg + chunk; if (end > n) end = n;
  int s = 0;
  for (int i = beg; i < end; ++i) s += counts_in[i];
  psum[t] = s;
  __syncthreads();
  for (int off = 1; off < 1024; off <<= 1){
    int v = (t >= off) ? psum[t - off] : 0;
    __syncthreads();
    psum[t] += v;
    __syncthreads();
  }
  int run = psum[t] - s;
  for (int i = beg; i < end; ++i){
    row_ptr[i] = run; run += counts_in[i]; counts_zero[i] = 0;
  }
  if (beg < n && end == n) row_ptr[n] = run;
}

__global__ void scatter_k(const int* __restrict__ ei, const int* __restrict__ row_ptr,
                          int* __restrict__ fill, int* __restrict__ esrc, int E, int n){
  int e = blockIdx.x * blockDim.x + threadIdx.x;
  if (e >= E + n) return;
  int s, d;
  if (e < E){ s = ei[e]; d = ei[E + e]; } else { s = e - E; d = s; }
  int pos = row_ptr[d] + atomicAdd(&fill[d], 1);
  esrc[pos] = s;
}

// ---------------- small-tile linear: 16 nodes/block ----------
// XMODE: 0 = fp32 Xf, 1 = bf16 Xb, 2 = runtime raw (dfl selects Xf/Xb view)
template<int K, bool ELU, bool ALPHA, bool OB16, int XMODE>
__global__ void linear_s_k(const float* __restrict__ Xf, const u16* __restrict__ Xb,
                           const float* __restrict__ W, const float* __restrict__ bias,
                           const float* __restrict__ a_src, const float* __restrict__ a_dst,
                           float* __restrict__ Y, u16* __restrict__ Yb,
                           float* __restrict__ asrc, float* __restrict__ adst,
                           const int* __restrict__ dfl, int n){
  constexpr int KC = (K > 64) ? 64 : K;
  __shared__ float wl[KC * 64];
  __shared__ float xr[16][KC + 4];
  int base = blockIdx.x * 16;
  int t = threadIdx.x;
  int lane = t & 63, wv = t >> 6;
  int node = wv * 4 + (lane >> 4);
  int jj = lane & 15;
  int f = (XMODE == 2) ? *dfl : 0;
  float ax = 0.f, ay = 0.f, az = 0.f, aw = 0.f;
  for (int kb = 0; kb < K; kb += KC){
    if (kb) __syncthreads();
    for (int q = t; q < KC * 16; q += 256)
      ((float4*)wl)[q] = ((const float4*)(W + (kb + (q >> 4)) * 64))[q & 15];
    for (int q = t; q < 16 * (KC / 4); q += 256){
      int nd = q / (KC / 4);
      int k4 = q - nd * (KC / 4);
      float4 v = make_float4(0.f, 0.f, 0.f, 0.f);
      if (base + nd < n){
        bool asf = (XMODE == 0) || (XMODE == 2 && f);
        if (asf){
          v = *(const float4*)(Xf + (base + nd) * K + kb + k4 * 4);
        } else {
          ushort4 v4 = *(const ushort4*)(Xb + (base + nd) * K + kb + k4 * 4);
          v = make_float4(bu2f(v4.x), bu2f(v4.y), bu2f(v4.z), bu2f(v4.w));
        }
      }
      *(float4*)(&xr[nd][k4 * 4]) = v;
    }
    __syncthreads();
#pragma unroll 4
    for (int k4 = 0; k4 < KC / 4; ++k4){
      float4 xv = *(const float4*)(&xr[node][k4 * 4]);
      float4 w0 = ((const float4*)wl)[(k4 * 4 + 0) * 16 + jj];
      float4 w1 = ((const float4*)wl)[(k4 * 4 + 1) * 16 + jj];
      float4 w2 = ((const float4*)wl)[(k4 * 4 + 2) * 16 + jj];
      float4 w3 = ((const float4*)wl)[(k4 * 4 + 3) * 16 + jj];
      ax += xv.x * w0.x + xv.y * w1.x + xv.z * w2.x + xv.w * w3.x;
      ay += xv.x * w0.y + xv.y * w1.y + xv.z * w2.y + xv.w * w3.y;
      az += xv.x * w0.z + xv.y * w1.z + xv.z * w2.z + xv.w * w3.z;
      aw += xv.x * w0.w + xv.y * w1.w + xv.z * w2.w + xv.w * w3.w;
    }
  }
  int gn = base + node;
  if (gn < n){
    float vx = ax, vy = ay, vz = az, vw = aw;
    if (ELU){
      float4 b = ((const float4*)bias)[jj];
      vx = eluf(ax + b.x); vy = eluf(ay + b.y); vz = eluf(az + b.z); vw = eluf(aw + b.w);
    }
    if (OB16){
      ushort4 o4;
      o4.x = f2bu(vx); o4.y = f2bu(vy); o4.z = f2bu(vz); o4.w = f2bu(vw);
      ((ushort4*)(Yb + gn * 64))[jj] = o4;
    } else {
      ((float4*)(Y + gn * 64))[jj] = make_float4(vx, vy, vz, vw);
    }
  }
  if (ALPHA){
    float4 as = *(const float4*)(a_src + 4 * jj);
    float4 ad = *(const float4*)(a_dst + 4 * jj);
    float s1 = ax * as.x + ay * as.y + az * as.z + aw * as.w;
    float s2 = ax * ad.x + ay * ad.y + az * ad.z + aw * ad.w;
    s1 = dpp_addx1(s1);
    s2 = dpp_addx1(s2);
    if (gn < n){
      int h = jj >> 1;
      if ((jj & 1) == 0) asrc[gn * 8 + h] = s1;
      else               adst[gn * 8 + h] = s2;
    }
  }
}

// ---------------- fused agg8, quad-packed gather, DPP reductions ------------
template<int NEXT>
__global__ void agg8f_k(const u16* __restrict__ hlin, const float* __restrict__ asrc,
                        const float* __restrict__ adst, const int* __restrict__ row_ptr,
                        const int* __restrict__ esrc, const float* __restrict__ bias,
                        const float* __restrict__ Wn,
                        const float* __restrict__ a_srcn, const float* __restrict__ a_dstn,
                        const float* __restrict__ avs, const float* __restrict__ avd,
                        u16* __restrict__ hout, u16* __restrict__ ylin,
                        float* __restrict__ asrco, float* __restrict__ adsto, int n){
  __shared__ float wl[NEXT == 1 ? 4096 : 1];
  __shared__ float os[4][64];
  if (NEXT == 1){
    for (int q = threadIdx.x; q < 1024; q += 256)
      ((float4*)wl)[q] = ((const float4*)Wn)[q];
    __syncthreads();
  }
  int node = (blockIdx.x * blockDim.x + threadIdx.x) >> 6;
  if (node >= n) return;
  int lane = threadIdx.x & 63;
  int wv = (threadIdx.x >> 6) & 3;
  int h = lane >> 3;                 // weight layout: head
  int j = lane & 7;                  //               edge slot
  int cp = lane & 15;                // gather layout: channel quad
  int q  = lane >> 4;                //               wave quarter
  int hh = cp >> 1;                  // head of channels 4cp..4cp+3
  int wlane0 = hh * 8 + q;
  int wlane1 = hh * 8 + 4 + q;
  int sclane = hh * 8;
  int beg = row_ptr[node], end = row_ptr[node + 1];
  float ad = adst[node * 8 + h];

  float m = -INFINITY, swp = 0.f;
  float4 acc = make_float4(0.f, 0.f, 0.f, 0.f);
  int p0 = beg + j;
  int   s_nx = 0;
  float l_nx = -INFINITY;
  if (p0 < end){ s_nx = esrc[p0]; l_nx = lrelu(asrc[s_nx * 8 + h] + ad); }
  for (int b0 = beg; b0 < end; b0 += 8){
    int   s = s_nx;
    float l = l_nx;
    int p2 = b0 + 8 + j;
    s_nx = 0; l_nx = -INFINITY;
    if (p2 < end){ s_nx = esrc[p2]; l_nx = lrelu(asrc[s_nx * 8 + h] + ad); }
    float bm = dpp_max8(l);                   // 8-lane max on VALU pipe
    float mn = fmaxf(m, bm);
    float scale = __expf(m - mn);
    swp *= scale; m = mn;
    float w = (b0 + j < end) ? __expf(l - m) : 0.f;
    swp += w;
    float scale_g = __shfl(scale, sclane);
    acc.x *= scale_g; acc.y *= scale_g; acc.z *= scale_g; acc.w *= scale_g;
    int s0 = __shfl(s, q);
    int s1 = __shfl(s, 4 + q);
    float w0 = __shfl(w, wlane0);
    float w1 = __shfl(w, wlane1);
    ushort4 hv0 = *(const ushort4*)(hlin + s0 * 64 + cp * 4);
    ushort4 hv1 = *(const ushort4*)(hlin + s1 * 64 + cp * 4);
    acc.x += bu2f(hv0.x) * w0 + bu2f(hv1.x) * w1;
    acc.y += bu2f(hv0.y) * w0 + bu2f(hv1.y) * w1;
    acc.z += bu2f(hv0.z) * w0 + bu2f(hv1.z) * w1;
    acc.w += bu2f(hv0.w) * w0 + bu2f(hv1.w) * w1;
  }
  acc.x += __shfl_xor(acc.x, 16); acc.x += __shfl_xor(acc.x, 32);
  acc.y += __shfl_xor(acc.y, 16); acc.y += __shfl_xor(acc.y, 32);
  acc.z += __shfl_xor(acc.z, 16); acc.z += __shfl_xor(acc.z, 32);
  acc.w += __shfl_xor(acc.w, 16); acc.w += __shfl_xor(acc.w, 32);
  swp = dpp_sum8(swp);
  float sw_g = __shfl(swp, sclane);
  float4 bv = ((const float4*)bias)[cp];
  float4 o4;
  o4.x = eluf(acc.x / sw_g + bv.x);
  o4.y = eluf(acc.y / sw_g + bv.y);
  o4.z = eluf(acc.z / sw_g + bv.z);
  o4.w = eluf(acc.w / sw_g + bv.w);

  if (NEXT == 1){
    if (lane < 16) *(float4*)(&os[wv][cp * 4]) = o4;   // same-wave RAW
    int jj = lane & 15, kk = lane >> 4;
    const float4* osr = (const float4*)(&os[wv][kk * 16]);
    float ax = 0.f, ay = 0.f, az = 0.f, aw = 0.f;
#pragma unroll
    for (int k4 = 0; k4 < 4; ++k4){
      float4 xv = osr[k4];                     // b128 LDS read (was 4x b32)
      float4 w0 = ((const float4*)wl)[(kk * 16 + k4 * 4 + 0) * 16 + jj];
      float4 w1 = ((const float4*)wl)[(kk * 16 + k4 * 4 + 1) * 16 + jj];
      float4 w2 = ((const float4*)wl)[(kk * 16 + k4 * 4 + 2) * 16 + jj];
      float4 w3 = ((const float4*)wl)[(kk * 16 + k4 * 4 + 3) * 16 + jj];
      ax += xv.x * w0.x + xv.y * w1.x + xv.z * w2.x + xv.w * w3.x;
      ay += xv.x * w0.y + xv.y * w1.y + xv.z * w2.y + xv.w * w3.y;
      az += xv.x * w0.z + xv.y * w1.z + xv.z * w2.z + xv.w * w3.z;
      aw += xv.x * w0.w + xv.y * w1.w + xv.z * w2.w + xv.w * w3.w;
    }
    ax += __shfl_xor(ax, 16); ax += __shfl_xor(ax, 32);
    ay += __shfl_xor(ay, 16); ay += __shfl_xor(ay, 32);
    az += __shfl_xor(az, 16); az += __shfl_xor(az, 32);
    aw += __shfl_xor(aw, 16); aw += __shfl_xor(aw, 32);
    if (lane < 16){
      ushort4 y4;
      y4.x = f2bu(ax); y4.y = f2bu(ay); y4.z = f2bu(az); y4.w = f2bu(aw);
      ((ushort4*)(ylin + node * 64))[jj] = y4;
      float4 as = *(const float4*)(a_srcn + 4 * jj);
      float4 adn = *(const float4*)(a_dstn + 4 * jj);
      float s1 = ax * as.x + ay * as.y + az * as.z + aw * as.w;
      float s2 = ax * adn.x + ay * adn.y + az * adn.z + aw * adn.w;
      s1 = dpp_addx1(s1);
      s2 = dpp_addx1(s2);
      int nh = jj >> 1;
      if ((jj & 1) == 0) asrco[node * 8 + nh] = s1;
      else               adsto[node * 8 + nh] = s2;
    }
  } else {
    if (lane < 16){
      ushort4 ho;
      ho.x = f2bu(o4.x); ho.y = f2bu(o4.y); ho.z = f2bu(o4.z); ho.w = f2bu(o4.w);
      ((ushort4*)(hout + node * 64))[cp] = ho;
      *(float4*)(&os[wv][cp * 4]) = o4;
    }
    int t8 = lane & 7, ah = (lane >> 3) & 3, sd = lane >> 5;
    const float* av = sd ? avd : avs;
    const float4* op = (const float4*)(&os[wv][t8 * 8]);     // 2x b128 (was 8x b32)
    const float4* ap = (const float4*)(av + ah * 64 + t8 * 8);
    float4 o0 = op[0], o1 = op[1];
    float4 a0 = ap[0], a1 = ap[1];
    float part = o0.x * a0.x + o0.y * a0.y + o0.z * a0.z + o0.w * a0.w
               + o1.x * a1.x + o1.y * a1.y + o1.z * a1.z + o1.w * a1.w;
    part = dpp_sum8(part);
    if (t8 == 0){
      if (sd == 0) asrco[node * 4 + ah] = part;
      else         adsto[node * 4 + ah] = part;
    }
  }
}

// Layer-4 gather: readlane broadcasts (SALU), DPP reductions, bf16 h3/z.
__global__ void aggz_k(const u16* __restrict__ h3, const float* __restrict__ asrc,
                       const float* __restrict__ adst, const int* __restrict__ row_ptr,
                       const int* __restrict__ esrc, u16* __restrict__ z, int n){
  int node = (blockIdx.x * blockDim.x + threadIdx.x) >> 6;
  if (node >= n) return;
  int lane = threadIdx.x & 63;
  int h = lane >> 4, j = lane & 15;
  int beg = row_ptr[node], end = row_ptr[node + 1];
  float4 adv = *(const float4*)(adst + node * 4);
  float adh = h == 0 ? adv.x : h == 1 ? adv.y : h == 2 ? adv.z : adv.w;

  float m = -INFINITY;
  float acc0 = 0.f, acc1 = 0.f, acc2 = 0.f, acc3 = 0.f, swp = 0.f;
  int p0 = beg + j;
  int   s_nx = 0;
  float l_nx = -INFINITY;
  if (p0 < end){ s_nx = esrc[p0]; l_nx = lrelu(asrc[s_nx * 4 + h] + adh); }
  for (int b0 = beg; b0 < end; b0 += 16){
    int   s = s_nx;
    float l = l_nx;
    int p2 = b0 + 16 + j;
    s_nx = 0; l_nx = -INFINITY;
    if (p2 < end){ s_nx = esrc[p2]; l_nx = lrelu(asrc[s_nx * 4 + h] + adh); }
    float bm = dpp_max16(l);
    float mn = fmaxf(m, bm);
    float scale = __expf(m - mn);
    acc0 *= scale; acc1 *= scale; acc2 *= scale; acc3 *= scale;
    swp *= scale; m = mn;
    float w = (b0 + j < end) ? __expf(l - m) : 0.f;
    swp += w;
    int cnt = end - b0; if (cnt > 16) cnt = 16;
#pragma unroll 4
    for (int i = 0; i < cnt; ++i){
      int   si = __builtin_amdgcn_readlane(s, i);
      float hv = bu2f(h3[si * 64 + lane]);
      float w0 = rl_f(w, i);
      float w1 = rl_f(w, 16 + i);
      float w2 = rl_f(w, 32 + i);
      float w3 = rl_f(w, 48 + i);
      acc0 += hv * w0; acc1 += hv * w1; acc2 += hv * w2; acc3 += hv * w3;
    }
  }
  swp = dpp_sum16(swp);
  float sw0 = __shfl(swp, 0), sw1 = __shfl(swp, 16);
  float sw2 = __shfl(swp, 32), sw3 = __shfl(swp, 48);
  int zb = node * 256;
  z[zb + lane]        = f2bu(acc0 / sw0);
  z[zb + 64 + lane]   = f2bu(acc1 / sw1);
  z[zb + 128 + lane]  = f2bu(acc2 / sw2);
  z[zb + 192 + lane]  = f2bu(acc3 / sw3);
}

// ---------------- pooling + head (bf16 h4) ----------------

__global__ void pool_k(const u16* __restrict__ h, const int* __restrict__ fidx,
                       const int* __restrict__ flag_arr, float* __restrict__ fp, int m){
  __shared__ float acc[512];
  for (int t = threadIdx.x; t < 512; t += blockDim.x) acc[t] = 0.f;
  __syncthreads();
  int lane = threadIdx.x & 63;
  int wave = (blockIdx.x * blockDim.x + threadIdx.x) >> 6;
  int nwaves = (gridDim.x * blockDim.x) >> 6;
  for (int i = wave; i < m; i += nwaves){
    int g = flag_arr[i];
    int node = fidx[i];
    atomicAdd(&acc[g * 64 + lane], bu2f(h[node * 64 + lane]));
  }
  __syncthreads();
  for (int t = threadIdx.x; t < 512; t += blockDim.x)
    atomicAdd(&fp[t], acc[t]);
}

__global__ void final_k(const float* __restrict__ fp, const u16* __restrict__ h,
                        const int* __restrict__ dec,
                        const float* __restrict__ Wp, const float* __restrict__ Wt,
                        const float* __restrict__ Wo, const float* __restrict__ bo,
                        void* __restrict__ out, const int* __restrict__ dflag){
  int g = threadIdx.x >> 6;
  int j = threadIdx.x & 63;
  const float* fr = fp + g * 64;
  const u16*   tr = h + dec[g] * 64;
  float a = 0.f, b = 0.f;
  for (int k = 0; k < 64; ++k){
    a += fr[k] * Wp[k * 64 + j];
    b += bu2f(tr[k]) * Wt[k * 64 + j];
  }
  float v = eluf(a) * Wo[j] + eluf(b) * Wo[64 + j];
  for (int off = 32; off > 0; off >>= 1) v += __shfl_down(v, off);
  if (j == 0){
    float r = v + bo[0];
    if (*dflag) ((float*)out)[g] = r;
    else        ((bf16*)out)[g] = __float2bfloat16(r);
  }
}

// ---------------- launch (12 dispatches) ----------------

extern "C" void kernel_launch(void* const* d_in, const int* in_sizes, int n_in,
                              void* d_out, int out_size, void* d_ws, size_t ws_size,
                              hipStream_t stream) {
  const int*  ei    = (const int*)d_in[1];
  const int*  fidx  = (const int*)d_in[2];
  const int*  flagg = (const int*)d_in[3];
  const int*  dec   = (const int*)d_in[4];

  const int N = in_sizes[0] / 16;   // 20000
  const int E = in_sizes[1] / 2;    // 320000
  const int M = in_sizes[2];        // 8000
  const int ET = E + N;

  // converted-to-fp32 arrays: layer1-3 weights/alphas/biases + b4 + head
  const int fidxs[17] = {5,6,7,8,9,10,11,12,13,14,15,16,20,21,22,23,24};
  ConvDesc cd;
  int tot = 0;
  for (int k = 0; k < 17; ++k){
    cd.src[k] = d_in[fidxs[k]];
    cd.off[k] = tot;
    tot += in_sizes[fidxs[k]];
  }
  cd.off[17] = tot;

  char* p = (char*)d_ws;
  auto carve = [&](size_t bytes) -> void* {
    void* r = (void*)p;
    p += (bytes + 255) & ~(size_t)255;
    return r;
  };
  int*   dflag   = (int*)carve(4);
  float* conv    = (float*)carve((size_t)tot * 4);
  u16*   hlA     = (u16*)carve((size_t)N * 64 * 2);
  u16*   hlB     = (u16*)carve((size_t)N * 64 * 2);
  u16*   h3buf   = (u16*)carve((size_t)N * 64 * 2);
  u16*   zbuf    = (u16*)carve((size_t)N * 256 * 2);
  u16*   h4buf   = (u16*)carve((size_t)N * 64 * 2);
  float* asrcA   = (float*)carve((size_t)N * 8 * 4);
  float* adstA   = (float*)carve((size_t)N * 8 * 4);
  float* asrcB   = (float*)carve((size_t)N * 8 * 4);
  float* adstB   = (float*)carve((size_t)N * 8 * 4);
  int*   counts  = (int*)carve((size_t)N * 4);
  int*   row_ptr = (int*)carve((size_t)(N + 1) * 4);
  int*   esrc    = (int*)carve((size_t)ET * 4);
  float* fp      = (float*)carve(8 * 64 * 4);
  float* avs     = (float*)carve(256 * 4);
  float* avd     = (float*)carve(256 * 4);
  float* wz      = (float*)carve(256 * 64 * 4);

  if ((size_t)(p - (char*)d_ws) > ws_size) return;

  const float* cW1 = conv + cd.off[0],  *cas1 = conv + cd.off[1],  *cad1 = conv + cd.off[2],  *cb1 = conv + cd.off[3];
  const float* cW2 = conv + cd.off[4],  *cas2 = conv + cd.off[5],  *cad2 = conv + cd.off[6],  *cb2 = conv + cd.off[7];
  const float* cW3 = conv + cd.off[8],  *cas3 = conv + cd.off[9],  *cad3 = conv + cd.off[10], *cb3 = conv + cd.off[11];
  const float* cb4 = conv + cd.off[12];
  const float* cWp = conv + cd.off[13], *cWt = conv + cd.off[14], *cWo = conv + cd.off[15], *cbo = conv + cd.off[16];

  const int TB = 256;
  int nprobe = in_sizes[0] < 4096 ? in_sizes[0] : 4096;
  int zb_blocks = (N + 255) / 256;
  int CB = (tot + 255) / 256;
  int EB = (ET + 255) / 256;

  detect_zero_k<<<zb_blocks, TB, 0, stream>>>((const u16*)d_in[0], nprobe, dflag, counts, fp, N);
  convcnt_k<<<CB + EB + 64, TB, 0, stream>>>(cd, conv, dflag, tot, ei, E, N, counts,
                                             d_in[17], d_in[18], d_in[19], avs, avd, wz, CB, EB);
  scan_k<<<1, 1024, 0, stream>>>(counts, counts, row_ptr, N);
  scatter_k<<<EB, TB, 0, stream>>>(ei, row_ptr, counts, esrc, E, N);

  int agg_blocks = (N * 64 + TB - 1) / TB;
  int ls_blocks  = (N + 15) / 16;

  // layer-1 linear reads x RAW (runtime fp32/bf16), bf16 out, + alpha1 -> A
  linear_s_k<16, false, true, true, 2><<<ls_blocks, TB, 0, stream>>>(
      (const float*)d_in[0], (const u16*)d_in[0], cW1, nullptr, cas1, cad1,
      nullptr, hlA, asrcA, adstA, dflag, N);
  agg8f_k<1><<<agg_blocks, TB, 0, stream>>>(hlA, asrcA, adstA, row_ptr, esrc, cb1,
                                            cW2, cas2, cad2, nullptr, nullptr,
                                            nullptr, hlB, asrcB, adstB, N);
  agg8f_k<1><<<agg_blocks, TB, 0, stream>>>(hlB, asrcB, adstB, row_ptr, esrc, cb2,
                                            cW3, cas3, cad3, nullptr, nullptr,
                                            nullptr, hlA, asrcA, adstA, N);
  agg8f_k<2><<<agg_blocks, TB, 0, stream>>>(hlA, asrcA, adstA, row_ptr, esrc, cb3,
                                            nullptr, nullptr, nullptr, avs, avd,
                                            h3buf, nullptr, asrcB, adstB, N);
  aggz_k<<<agg_blocks, TB, 0, stream>>>(h3buf, asrcB, adstB, row_ptr, esrc, zbuf, N);
  linear_s_k<256, true, false, true, 1><<<ls_blocks, TB, 0, stream>>>(
      nullptr, zbuf, wz, cb4, nullptr, nullptr, nullptr, h4buf, nullptr, nullptr, nullptr, N);
  pool_k<<<64, TB, 0, stream>>>(h4buf, fidx, flagg, fp, M);
  final_k<<<1, 512, 0, stream>>>(fp, h4buf, dec, cWp, cWt, cWo, cbo, d_out, dflag);
}

// Round 18
// 316.027 us; speedup vs baseline: 1.0238x; 1.0182x over previous
//
#include <hip/hip_runtime.h>
#include <hip/hip_bf16.h>
#include <math.h>

typedef __hip_bfloat16 bf16;
typedef unsigned short u16;

__device__ __forceinline__ float b2f(bf16 v){ return __bfloat162float(v); }
__device__ __forceinline__ u16 f2bu(float f){
  bf16 h = __float2bfloat16(f);
  return *reinterpret_cast<u16*>(&h);
}
__device__ __forceinline__ float bu2f(u16 u){
  bf16 h = *reinterpret_cast<bf16*>(&u);
  return __bfloat162float(h);
}
__device__ __forceinline__ float eluf(float x){ return x > 0.f ? x : __expf(x) - 1.f; }
__device__ __forceinline__ float lrelu(float x){ return x > 0.f ? x : 0.2f * x; }
__device__ __forceinline__ float ldr(const void* p, int i, int f){
  return f ? ((const float*)p)[i] : b2f(((const bf16*)p)[i]);
}
__device__ __forceinline__ float rl_f(float v, int lane){
  return __int_as_float(__builtin_amdgcn_readlane(__float_as_int(v), lane));
}

// ---- DPP cross-lane (VALU pipe, not DS) -----------------------------------
#define DPP_F(x, ctrl) __int_as_float(__builtin_amdgcn_update_dpp(0, __float_as_int(x), (ctrl), 0xF, 0xF, true))
__device__ __forceinline__ float dpp_max8(float x){
  x = fmaxf(x, DPP_F(x, 0xB1));
  x = fmaxf(x, DPP_F(x, 0x4E));
  x = fmaxf(x, DPP_F(x, 0x141));
  return x;
}
__device__ __forceinline__ float dpp_sum8(float x){
  x += DPP_F(x, 0xB1);
  x += DPP_F(x, 0x4E);
  x += DPP_F(x, 0x141);
  return x;
}
__device__ __forceinline__ float dpp_max16(float x){
  x = fmaxf(x, DPP_F(x, 0xB1));
  x = fmaxf(x, DPP_F(x, 0x4E));
  x = fmaxf(x, DPP_F(x, 0x141));
  x = fmaxf(x, DPP_F(x, 0x140));
  return x;
}
__device__ __forceinline__ float dpp_sum16(float x){
  x += DPP_F(x, 0xB1);
  x += DPP_F(x, 0x4E);
  x += DPP_F(x, 0x141);
  x += DPP_F(x, 0x140);
  return x;
}
__device__ __forceinline__ float dpp_addx1(float x){ return x + DPP_F(x, 0xB1); }

// ---------------- detect dtype + zero counts/fp (merged) --------------------
__global__ void detect_zero_k(const u16* __restrict__ x, int nprobe, int* __restrict__ flag,
                              int* __restrict__ counts, float* __restrict__ fp, int n){
  int i = blockIdx.x * 256 + threadIdx.x;
  if (i < n) counts[i] = 0;
  if (i < 512) fp[i] = 0.f;
  if (blockIdx.x == 0){
    __shared__ int bad_s;
    if (threadIdx.x == 0) bad_s = 0;
    __syncthreads();
    int bad = 0;
    for (int k = threadIdx.x; k < nprobe; k += 256){
      int ex = (x[k] >> 7) & 0xFF;
      if (ex >= 0xC6) bad = 1;
    }
    if (bad) atomicOr(&bad_s, 1);
    __syncthreads();
    if (threadIdx.x == 0) *flag = bad_s;
  }
}

// ---------------- convert(weights only) + count_edges + prep4 ---------------
struct ConvDesc {
  const void* src[17];
  int off[18];
};

__global__ void convcnt_k(ConvDesc d, float* __restrict__ out, const int* __restrict__ flag,
                          int total, const int* __restrict__ ei, int E, int n,
                          int* __restrict__ counts,
                          const void* __restrict__ W4r, const void* __restrict__ as4r,
                          const void* __restrict__ ad4r, float* __restrict__ avs,
                          float* __restrict__ avd, float* __restrict__ Wz,
                          int CB, int EB){
  int b = blockIdx.x;
  int f = *flag;
  if (b < CB){
    int i = b * 256 + threadIdx.x;
    if (i >= total) return;
    int a = 0;
    while (i >= d.off[a + 1]) ++a;
    out[i] = ldr(d.src[a], i - d.off[a], f);
  } else if (b < CB + EB){
    int e = (b - CB) * 256 + threadIdx.x;
    if (e >= E + n) return;
    int dd = (e < E) ? ei[E + e] : (e - E);
    atomicAdd(&counts[dd], 1);
  } else {
    int pb = b - CB - EB;                     // 0..63
    int g = pb * 256 + threadIdx.x;           // < 16384
    int r = g >> 6, c = g & 63;
    int h = r >> 6, k = r & 63;
    Wz[r * 64 + c] = 0.25f * ldr(W4r, k * 256 + h * 64 + c, f);
    if (pb == 0){
      int t = threadIdx.x;
      int th = t >> 6, tk = t & 63;
      float s1 = 0.f, s2 = 0.f;
      for (int cc = 0; cc < 64; ++cc){
        float w = ldr(W4r, tk * 256 + th * 64 + cc, f);
        s1 += w * ldr(as4r, th * 64 + cc, f);
        s2 += w * ldr(ad4r, th * 64 + cc, f);
      }
      avs[t] = s1;
      avd[t] = s2;
    }
  }
}

// ---------------- CSR scan + scatter ----------------

__global__ void scan_k(const int* __restrict__ counts_in, int* __restrict__ counts_zero,
                       int* __restrict__ row_ptr, int n){
  __shared__ int psum[1024];
  int t = threadIdx.x;
  int chunk = (n + 1023) >> 10;
  int beg = t * chunk;
  int end = beg + chunk; if (end > n) end = n;
  int s = 0;
  for (int i = beg; i < end; ++i) s += counts_in[i];
  psum[t] = s;
  __syncthreads();
  for (int off = 1; off < 1024; off <<= 1){
    int v = (t >= off) ? psum[t - off] : 0;
    __syncthreads();
    psum[t] += v;
    __syncthreads();
  }
  int run = psum[t] - s;
  for (int i = beg; i < end; ++i){
    row_ptr[i] = run; run += counts_in[i]; counts_zero[i] = 0;
  }
  if (beg < n && end == n) row_ptr[n] = run;
}

__global__ void scatter_k(const int* __restrict__ ei, const int* __restrict__ row_ptr,
                          int* __restrict__ fill, int* __restrict__ esrc, int E, int n){
  int e = blockIdx.x * blockDim.x + threadIdx.x;
  if (e >= E + n) return;
  int s, d;
  if (e < E){ s = ei[e]; d = ei[E + e]; } else { s = e - E; d = s; }
  int pos = row_ptr[d] + atomicAdd(&fill[d], 1);
  esrc[pos] = s;
}

// ---------------- small-tile linear: 16 nodes/block ----------
// XMODE: 0 = fp32 Xf, 1 = bf16 Xb, 2 = runtime raw (dfl selects Xf/Xb view)
template<int K, bool ELU, bool ALPHA, bool OB16, int XMODE>
__global__ void linear_s_k(const float* __restrict__ Xf, const u16* __restrict__ Xb,
                           const float* __restrict__ W, const float* __restrict__ bias,
                           const float* __restrict__ a_src, const float* __restrict__ a_dst,
                           float* __restrict__ Y, u16* __restrict__ Yb,
                           float* __restrict__ asrc, float* __restrict__ adst,
                           const int* __restrict__ dfl, int n){
  constexpr int KC = (K > 64) ? 64 : K;
  __shared__ float wl[KC * 64];
  __shared__ float xr[16][KC + 4];
  int base = blockIdx.x * 16;
  int t = threadIdx.x;
  int lane = t & 63, wv = t >> 6;
  int node = wv * 4 + (lane >> 4);
  int jj = lane & 15;
  int f = (XMODE == 2) ? *dfl : 0;
  float ax = 0.f, ay = 0.f, az = 0.f, aw = 0.f;
  for (int kb = 0; kb < K; kb += KC){
    if (kb) __syncthreads();
    for (int q = t; q < KC * 16; q += 256)
      ((float4*)wl)[q] = ((const float4*)(W + (kb + (q >> 4)) * 64))[q & 15];
    for (int q = t; q < 16 * (KC / 4); q += 256){
      int nd = q / (KC / 4);
      int k4 = q - nd * (KC / 4);
      float4 v = make_float4(0.f, 0.f, 0.f, 0.f);
      if (base + nd < n){
        bool asf = (XMODE == 0) || (XMODE == 2 && f);
        if (asf){
          v = *(const float4*)(Xf + (base + nd) * K + kb + k4 * 4);
        } else {
          ushort4 v4 = *(const ushort4*)(Xb + (base + nd) * K + kb + k4 * 4);
          v = make_float4(bu2f(v4.x), bu2f(v4.y), bu2f(v4.z), bu2f(v4.w));
        }
      }
      *(float4*)(&xr[nd][k4 * 4]) = v;
    }
    __syncthreads();
#pragma unroll 4
    for (int k4 = 0; k4 < KC / 4; ++k4){
      float4 xv = *(const float4*)(&xr[node][k4 * 4]);
      float4 w0 = ((const float4*)wl)[(k4 * 4 + 0) * 16 + jj];
      float4 w1 = ((const float4*)wl)[(k4 * 4 + 1) * 16 + jj];
      float4 w2 = ((const float4*)wl)[(k4 * 4 + 2) * 16 + jj];
      float4 w3 = ((const float4*)wl)[(k4 * 4 + 3) * 16 + jj];
      ax += xv.x * w0.x + xv.y * w1.x + xv.z * w2.x + xv.w * w3.x;
      ay += xv.x * w0.y + xv.y * w1.y + xv.z * w2.y + xv.w * w3.y;
      az += xv.x * w0.z + xv.y * w1.z + xv.z * w2.z + xv.w * w3.z;
      aw += xv.x * w0.w + xv.y * w1.w + xv.z * w2.w + xv.w * w3.w;
    }
  }
  int gn = base + node;
  if (gn < n){
    float vx = ax, vy = ay, vz = az, vw = aw;
    if (ELU){
      float4 b = ((const float4*)bias)[jj];
      vx = eluf(ax + b.x); vy = eluf(ay + b.y); vz = eluf(az + b.z); vw = eluf(aw + b.w);
    }
    if (OB16){
      ushort4 o4;
      o4.x = f2bu(vx); o4.y = f2bu(vy); o4.z = f2bu(vz); o4.w = f2bu(vw);
      ((ushort4*)(Yb + gn * 64))[jj] = o4;
    } else {
      ((float4*)(Y + gn * 64))[jj] = make_float4(vx, vy, vz, vw);
    }
  }
  if (ALPHA){
    float4 as = *(const float4*)(a_src + 4 * jj);
    float4 ad = *(const float4*)(a_dst + 4 * jj);
    float s1 = ax * as.x + ay * as.y + az * as.z + aw * as.w;
    float s2 = ax * ad.x + ay * ad.y + az * ad.z + aw * ad.w;
    s1 = dpp_addx1(s1);
    s2 = dpp_addx1(s2);
    if (gn < n){
      int h = jj >> 1;
      if ((jj & 1) == 0) asrc[gn * 8 + h] = s1;
      else               adst[gn * 8 + h] = s2;
    }
  }
}

// ---------------- fused agg8, quad-packed gather, DPP reductions ------------
template<int NEXT>
__global__ void agg8f_k(const u16* __restrict__ hlin, const float* __restrict__ asrc,
                        const float* __restrict__ adst, const int* __restrict__ row_ptr,
                        const int* __restrict__ esrc, const float* __restrict__ bias,
                        const float* __restrict__ Wn,
                        const float* __restrict__ a_srcn, const float* __restrict__ a_dstn,
                        const float* __restrict__ avs, const float* __restrict__ avd,
                        u16* __restrict__ hout, u16* __restrict__ ylin,
                        float* __restrict__ asrco, float* __restrict__ adsto, int n){
  __shared__ float wl[NEXT == 1 ? 4096 : 1];
  __shared__ float os[4][64];
  if (NEXT == 1){
    for (int q = threadIdx.x; q < 1024; q += 256)
      ((float4*)wl)[q] = ((const float4*)Wn)[q];
    __syncthreads();
  }
  int node = (blockIdx.x * blockDim.x + threadIdx.x) >> 6;
  if (node >= n) return;
  int lane = threadIdx.x & 63;
  int wv = (threadIdx.x >> 6) & 3;
  int h = lane >> 3;                 // weight layout: head
  int j = lane & 7;                  //               edge slot
  int cp = lane & 15;                // gather layout: channel quad
  int q  = lane >> 4;                //               wave quarter
  int hh = cp >> 1;                  // head of channels 4cp..4cp+3
  int wlane0 = hh * 8 + q;
  int wlane1 = hh * 8 + 4 + q;
  int sclane = hh * 8;
  int beg = row_ptr[node], end = row_ptr[node + 1];
  float ad = adst[node * 8 + h];

  float m = -INFINITY, swp = 0.f;
  float4 acc = make_float4(0.f, 0.f, 0.f, 0.f);
  int p0 = beg + j;
  int   s_nx = 0;
  float l_nx = -INFINITY;
  if (p0 < end){ s_nx = esrc[p0]; l_nx = lrelu(asrc[s_nx * 8 + h] + ad); }
  for (int b0 = beg; b0 < end; b0 += 8){
    int   s = s_nx;
    float l = l_nx;
    int p2 = b0 + 8 + j;
    s_nx = 0; l_nx = -INFINITY;
    if (p2 < end){ s_nx = esrc[p2]; l_nx = lrelu(asrc[s_nx * 8 + h] + ad); }
    float bm = dpp_max8(l);                   // 8-lane max on VALU pipe
    float mn = fmaxf(m, bm);
    float scale = __expf(m - mn);
    swp *= scale; m = mn;
    float w = (b0 + j < end) ? __expf(l - m) : 0.f;
    swp += w;
    float scale_g = __shfl(scale, sclane);
    acc.x *= scale_g; acc.y *= scale_g; acc.z *= scale_g; acc.w *= scale_g;
    int s0 = __shfl(s, q);
    int s1 = __shfl(s, 4 + q);
    float w0 = __shfl(w, wlane0);
    float w1 = __shfl(w, wlane1);
    ushort4 hv0 = *(const ushort4*)(hlin + s0 * 64 + cp * 4);
    ushort4 hv1 = *(const ushort4*)(hlin + s1 * 64 + cp * 4);
    acc.x += bu2f(hv0.x) * w0 + bu2f(hv1.x) * w1;
    acc.y += bu2f(hv0.y) * w0 + bu2f(hv1.y) * w1;
    acc.z += bu2f(hv0.z) * w0 + bu2f(hv1.z) * w1;
    acc.w += bu2f(hv0.w) * w0 + bu2f(hv1.w) * w1;
  }
  acc.x += __shfl_xor(acc.x, 16); acc.x += __shfl_xor(acc.x, 32);
  acc.y += __shfl_xor(acc.y, 16); acc.y += __shfl_xor(acc.y, 32);
  acc.z += __shfl_xor(acc.z, 16); acc.z += __shfl_xor(acc.z, 32);
  acc.w += __shfl_xor(acc.w, 16); acc.w += __shfl_xor(acc.w, 32);
  swp = dpp_sum8(swp);
  float sw_g = __shfl(swp, sclane);
  float4 bv = ((const float4*)bias)[cp];
  float4 o4;
  o4.x = eluf(acc.x / sw_g + bv.x);
  o4.y = eluf(acc.y / sw_g + bv.y);
  o4.z = eluf(acc.z / sw_g + bv.z);
  o4.w = eluf(acc.w / sw_g + bv.w);

  if (NEXT == 1){
    if (lane < 16) *(float4*)(&os[wv][cp * 4]) = o4;   // same-wave RAW
    int jj = lane & 15, kk = lane >> 4;
    const float4* osr = (const float4*)(&os[wv][kk * 16]);
    float ax = 0.f, ay = 0.f, az = 0.f, aw = 0.f;
#pragma unroll
    for (int k4 = 0; k4 < 4; ++k4){
      float4 xv = osr[k4];                     // b128 LDS read
      float4 w0 = ((const float4*)wl)[(kk * 16 + k4 * 4 + 0) * 16 + jj];
      float4 w1 = ((const float4*)wl)[(kk * 16 + k4 * 4 + 1) * 16 + jj];
      float4 w2 = ((const float4*)wl)[(kk * 16 + k4 * 4 + 2) * 16 + jj];
      float4 w3 = ((const float4*)wl)[(kk * 16 + k4 * 4 + 3) * 16 + jj];
      ax += xv.x * w0.x + xv.y * w1.x + xv.z * w2.x + xv.w * w3.x;
      ay += xv.x * w0.y + xv.y * w1.y + xv.z * w2.y + xv.w * w3.y;
      az += xv.x * w0.z + xv.y * w1.z + xv.z * w2.z + xv.w * w3.z;
      aw += xv.x * w0.w + xv.y * w1.w + xv.z * w2.w + xv.w * w3.w;
    }
    ax += __shfl_xor(ax, 16); ax += __shfl_xor(ax, 32);
    ay += __shfl_xor(ay, 16); ay += __shfl_xor(ay, 32);
    az += __shfl_xor(az, 16); az += __shfl_xor(az, 32);
    aw += __shfl_xor(aw, 16); aw += __shfl_xor(aw, 32);
    if (lane < 16){
      ushort4 y4;
      y4.x = f2bu(ax); y4.y = f2bu(ay); y4.z = f2bu(az); y4.w = f2bu(aw);
      ((ushort4*)(ylin + node * 64))[jj] = y4;
      float4 as = *(const float4*)(a_srcn + 4 * jj);
      float4 adn = *(const float4*)(a_dstn + 4 * jj);
      float s1 = ax * as.x + ay * as.y + az * as.z + aw * as.w;
      float s2 = ax * adn.x + ay * adn.y + az * adn.z + aw * adn.w;
      s1 = dpp_addx1(s1);
      s2 = dpp_addx1(s2);
      int nh = jj >> 1;
      if ((jj & 1) == 0) asrco[node * 8 + nh] = s1;
      else               adsto[node * 8 + nh] = s2;
    }
  } else {
    if (lane < 16){
      ushort4 ho;
      ho.x = f2bu(o4.x); ho.y = f2bu(o4.y); ho.z = f2bu(o4.z); ho.w = f2bu(o4.w);
      ((ushort4*)(hout + node * 64))[cp] = ho;
      *(float4*)(&os[wv][cp * 4]) = o4;
    }
    int t8 = lane & 7, ah = (lane >> 3) & 3, sd = lane >> 5;
    const float* av = sd ? avd : avs;
    const float4* op = (const float4*)(&os[wv][t8 * 8]);
    const float4* ap = (const float4*)(av + ah * 64 + t8 * 8);
    float4 o0 = op[0], o1 = op[1];
    float4 a0 = ap[0], a1 = ap[1];
    float part = o0.x * a0.x + o0.y * a0.y + o0.z * a0.z + o0.w * a0.w
               + o1.x * a1.x + o1.y * a1.y + o1.z * a1.z + o1.w * a1.w;
    part = dpp_sum8(part);
    if (t8 == 0){
      if (sd == 0) asrco[node * 4 + ah] = part;
      else         adsto[node * 4 + ah] = part;
    }
  }
}

// Layer-4 gather: readlane broadcasts (SALU), DPP reductions, bf16 h3/z.
__global__ void aggz_k(const u16* __restrict__ h3, const float* __restrict__ asrc,
                       const float* __restrict__ adst, const int* __restrict__ row_ptr,
                       const int* __restrict__ esrc, u16* __restrict__ z, int n){
  int node = (blockIdx.x * blockDim.x + threadIdx.x) >> 6;
  if (node >= n) return;
  int lane = threadIdx.x & 63;
  int h = lane >> 4, j = lane & 15;
  int beg = row_ptr[node], end = row_ptr[node + 1];
  float4 adv = *(const float4*)(adst + node * 4);
  float adh = h == 0 ? adv.x : h == 1 ? adv.y : h == 2 ? adv.z : adv.w;

  float m = -INFINITY;
  float acc0 = 0.f, acc1 = 0.f, acc2 = 0.f, acc3 = 0.f, swp = 0.f;
  int p0 = beg + j;
  int   s_nx = 0;
  float l_nx = -INFINITY;
  if (p0 < end){ s_nx = esrc[p0]; l_nx = lrelu(asrc[s_nx * 4 + h] + adh); }
  for (int b0 = beg; b0 < end; b0 += 16){
    int   s = s_nx;
    float l = l_nx;
    int p2 = b0 + 16 + j;
    s_nx = 0; l_nx = -INFINITY;
    if (p2 < end){ s_nx = esrc[p2]; l_nx = lrelu(asrc[s_nx * 4 + h] + adh); }
    float bm = dpp_max16(l);
    float mn = fmaxf(m, bm);
    float scale = __expf(m - mn);
    acc0 *= scale; acc1 *= scale; acc2 *= scale; acc3 *= scale;
    swp *= scale; m = mn;
    float w = (b0 + j < end) ? __expf(l - m) : 0.f;
    swp += w;
    int cnt = end - b0; if (cnt > 16) cnt = 16;
#pragma unroll 4
    for (int i = 0; i < cnt; ++i){
      int   si = __builtin_amdgcn_readlane(s, i);
      float hv = bu2f(h3[si * 64 + lane]);
      float w0 = rl_f(w, i);
      float w1 = rl_f(w, 16 + i);
      float w2 = rl_f(w, 32 + i);
      float w3 = rl_f(w, 48 + i);
      acc0 += hv * w0; acc1 += hv * w1; acc2 += hv * w2; acc3 += hv * w3;
    }
  }
  swp = dpp_sum16(swp);
  float sw0 = __shfl(swp, 0), sw1 = __shfl(swp, 16);
  float sw2 = __shfl(swp, 32), sw3 = __shfl(swp, 48);
  int zb = node * 256;
  z[zb + lane]        = f2bu(acc0 / sw0);
  z[zb + 64 + lane]   = f2bu(acc1 / sw1);
  z[zb + 128 + lane]  = f2bu(acc2 / sw2);
  z[zb + 192 + lane]  = f2bu(acc3 / sw3);
}

// ---------------- pooling + head (bf16 h4) ----------------

__global__ void pool_k(const u16* __restrict__ h, const int* __restrict__ fidx,
                       const int* __restrict__ flag_arr, float* __restrict__ fp, int m){
  __shared__ float acc[512];
  for (int t = threadIdx.x; t < 512; t += blockDim.x) acc[t] = 0.f;
  __syncthreads();
  int lane = threadIdx.x & 63;
  int wave = (blockIdx.x * blockDim.x + threadIdx.x) >> 6;
  int nwaves = (gridDim.x * blockDim.x) >> 6;
  for (int i = wave; i < m; i += nwaves){
    int g = flag_arr[i];
    int node = fidx[i];
    atomicAdd(&acc[g * 64 + lane], bu2f(h[node * 64 + lane]));
  }
  __syncthreads();
  for (int t = threadIdx.x; t < 512; t += blockDim.x)
    atomicAdd(&fp[t], acc[t]);
}

__global__ void final_k(const float* __restrict__ fp, const u16* __restrict__ h,
                        const int* __restrict__ dec,
                        const float* __restrict__ Wp, const float* __restrict__ Wt,
                        const float* __restrict__ Wo, const float* __restrict__ bo,
                        void* __restrict__ out, const int* __restrict__ dflag){
  int g = threadIdx.x >> 6;
  int j = threadIdx.x & 63;
  const float* fr = fp + g * 64;
  const u16*   tr = h + dec[g] * 64;
  float a = 0.f, b = 0.f;
  for (int k = 0; k < 64; ++k){
    a += fr[k] * Wp[k * 64 + j];
    b += bu2f(tr[k]) * Wt[k * 64 + j];
  }
  float v = eluf(a) * Wo[j] + eluf(b) * Wo[64 + j];
  for (int off = 32; off > 0; off >>= 1) v += __shfl_down(v, off);
  if (j == 0){
    float r = v + bo[0];
    if (*dflag) ((float*)out)[g] = r;
    else        ((bf16*)out)[g] = __float2bfloat16(r);
  }
}

// ---------------- launch (12 dispatches) ----------------

extern "C" void kernel_launch(void* const* d_in, const int* in_sizes, int n_in,
                              void* d_out, int out_size, void* d_ws, size_t ws_size,
                              hipStream_t stream) {
  const int*  ei    = (const int*)d_in[1];
  const int*  fidx  = (const int*)d_in[2];
  const int*  flagg = (const int*)d_in[3];
  const int*  dec   = (const int*)d_in[4];

  const int N = in_sizes[0] / 16;   // 20000
  const int E = in_sizes[1] / 2;    // 320000
  const int M = in_sizes[2];        // 8000
  const int ET = E + N;

  // converted-to-fp32 arrays: layer1-3 weights/alphas/biases + b4 + head
  const int fidxs[17] = {5,6,7,8,9,10,11,12,13,14,15,16,20,21,22,23,24};
  ConvDesc cd;
  int tot = 0;
  for (int k = 0; k < 17; ++k){
    cd.src[k] = d_in[fidxs[k]];
    cd.off[k] = tot;
    tot += in_sizes[fidxs[k]];
  }
  cd.off[17] = tot;

  char* p = (char*)d_ws;
  auto carve = [&](size_t bytes) -> void* {
    void* r = (void*)p;
    p += (bytes + 255) & ~(size_t)255;
    return r;
  };
  int*   dflag   = (int*)carve(4);
  float* conv    = (float*)carve((size_t)tot * 4);
  u16*   hlA     = (u16*)carve((size_t)N * 64 * 2);
  u16*   hlB     = (u16*)carve((size_t)N * 64 * 2);
  u16*   h3buf   = (u16*)carve((size_t)N * 64 * 2);
  u16*   zbuf    = (u16*)carve((size_t)N * 256 * 2);
  u16*   h4buf   = (u16*)carve((size_t)N * 64 * 2);
  float* asrcA   = (float*)carve((size_t)N * 8 * 4);
  float* adstA   = (float*)carve((size_t)N * 8 * 4);
  float* asrcB   = (float*)carve((size_t)N * 8 * 4);
  float* adstB   = (float*)carve((size_t)N * 8 * 4);
  int*   counts  = (int*)carve((size_t)N * 4);
  int*   row_ptr = (int*)carve((size_t)(N + 1) * 4);
  int*   esrc    = (int*)carve((size_t)ET * 4);
  float* fp      = (float*)carve(8 * 64 * 4);
  float* avs     = (float*)carve(256 * 4);
  float* avd     = (float*)carve(256 * 4);
  float* wz      = (float*)carve(256 * 64 * 4);

  if ((size_t)(p - (char*)d_ws) > ws_size) return;

  const float* cW1 = conv + cd.off[0],  *cas1 = conv + cd.off[1],  *cad1 = conv + cd.off[2],  *cb1 = conv + cd.off[3];
  const float* cW2 = conv + cd.off[4],  *cas2 = conv + cd.off[5],  *cad2 = conv + cd.off[6],  *cb2 = conv + cd.off[7];
  const float* cW3 = conv + cd.off[8],  *cas3 = conv + cd.off[9],  *cad3 = conv + cd.off[10], *cb3 = conv + cd.off[11];
  const float* cb4 = conv + cd.off[12];
  const float* cWp = conv + cd.off[13], *cWt = conv + cd.off[14], *cWo = conv + cd.off[15], *cbo = conv + cd.off[16];

  const int TB = 256;
  int nprobe = in_sizes[0] < 4096 ? in_sizes[0] : 4096;
  int zb_blocks = (N + 255) / 256;
  int CB = (tot + 255) / 256;
  int EB = (ET + 255) / 256;

  detect_zero_k<<<zb_blocks, TB, 0, stream>>>((const u16*)d_in[0], nprobe, dflag, counts, fp, N);
  convcnt_k<<<CB + EB + 64, TB, 0, stream>>>(cd, conv, dflag, tot, ei, E, N, counts,
                                             d_in[17], d_in[18], d_in[19], avs, avd, wz, CB, EB);
  scan_k<<<1, 1024, 0, stream>>>(counts, counts, row_ptr, N);
  scatter_k<<<EB, TB, 0, stream>>>(ei, row_ptr, counts, esrc, E, N);

  int agg_blocks = (N * 64 + TB - 1) / TB;
  int ls_blocks  = (N + 15) / 16;

  // layer-1 linear reads x RAW (runtime fp32/bf16), bf16 out, + alpha1 -> A
  linear_s_k<16, false, true, true, 2><<<ls_blocks, TB, 0, stream>>>(
      (const float*)d_in[0], (const u16*)d_in[0], cW1, nullptr, cas1, cad1,
      nullptr, hlA, asrcA, adstA, dflag, N);
  agg8f_k<1><<<agg_blocks, TB, 0, stream>>>(hlA, asrcA, adstA, row_ptr, esrc, cb1,
                                            cW2, cas2, cad2, nullptr, nullptr,
                                            nullptr, hlB, asrcB, adstB, N);
  agg8f_k<1><<<agg_blocks, TB, 0, stream>>>(hlB, asrcB, adstB, row_ptr, esrc, cb2,
                                            cW3, cas3, cad3, nullptr, nullptr,
                                            nullptr, hlA, asrcA, adstA, N);
  agg8f_k<2><<<agg_blocks, TB, 0, stream>>>(hlA, asrcA, adstA, row_ptr, esrc, cb3,
                                            nullptr, nullptr, nullptr, avs, avd,
                                            h3buf, nullptr, asrcB, adstB, N);
  aggz_k<<<agg_blocks, TB, 0, stream>>>(h3buf, asrcB, adstB, row_ptr, esrc, zbuf, N);
  linear_s_k<256, true, false, true, 1><<<ls_blocks, TB, 0, stream>>>(
      nullptr, zbuf, wz, cb4, nullptr, nullptr, nullptr, h4buf, nullptr, nullptr, nullptr, N);
  pool_k<<<64, TB, 0, stream>>>(h4buf, fidx, flagg, fp, M);
  final_k<<<1, 512, 0, stream>>>(fp, h4buf, dec, cWp, cWt, cWo, cbo, d_out, dflag);
}